// Round 1
// baseline (772.164 us; speedup 1.0000x reference)
//
#include <hip/hip_runtime.h>
#include <math.h>

#define NVOX 110592   // 48*48*48

__device__ __forceinline__ void fma4(float4& a, const float4& w, const float4& f) {
    a.x = fmaf(w.x, f.x, a.x);
    a.y = fmaf(w.y, f.y, a.y);
    a.z = fmaf(w.z, f.z, a.z);
    a.w = fmaf(w.w, f.w, a.w);
}
__device__ __forceinline__ void fmas4(float4& a, const float4& xv, float p) {
    a.x = fmaf(xv.x, p, a.x);
    a.y = fmaf(xv.y, p, a.y);
    a.z = fmaf(xv.z, p, a.z);
    a.w = fmaf(xv.w, p, a.w);
}
__device__ __forceinline__ float comp4(const float4& v, int j) {
    return j == 0 ? v.x : (j == 1 ? v.y : (j == 2 ? v.z : v.w));
}

// ---------------------------------------------------------------------------
// K0: transpose w1 [64][32][27] -> w1t [64][27][32]  (ci contiguous for float4)
// ---------------------------------------------------------------------------
__global__ void k_w1t(const float* __restrict__ w1, float* __restrict__ w1t) {
    int e = blockIdx.x * 256 + threadIdx.x;
    if (e >= 64 * 32 * 27) return;
    int oc = e / 864;
    int r = e - oc * 864;
    int ci = r / 27;
    int tap = r - ci * 27;
    w1t[(oc * 27 + tap) * 32 + ci] = w1[e];
}

// ---------------------------------------------------------------------------
// K1: conv3x3x3 (replicate pad) + SiLU.  One block per (d,h) row (48 voxels).
// LDS: feat[9 dzdy][50 px][32 ci], column stride padded to 36 floats
//      (36 = 4 mod 32 -> conflict-free b128 across px-varying lanes).
// Thread (tx 0..15, ty 0..15): oc = ty*4..+3, w = tx + {0,16,32}.
// ---------------------------------------------------------------------------
__global__ __launch_bounds__(256, 2) void k_conv1(
    const float* __restrict__ feat, const float* __restrict__ w1t,
    const float* __restrict__ b1, float* __restrict__ hout)
{
    __shared__ float lds[450 * 36];          // 64.8 KB
    float4* lds4 = (float4*)lds;
    const float4* w1t4 = (const float4*)w1t;
    int bx = blockIdx.x;
    int d = bx / 48, hh = bx - d * 48;
    int t = threadIdx.x;

    // stage features (replicate-clamped), coalesced along px
    for (int i = t; i < 3600; i += 256) {
        int cq = i / 450;                    // 0..7 (ci quad)
        int col = i - cq * 450;              // (dzdy, px)
        int dzdy = col / 50;
        int px = col - dzdy * 50;
        int dz = dzdy / 3, dy = dzdy - dz * 3;
        int zz = min(max(d + dz - 1, 0), 47);
        int yy = min(max(hh + dy - 1, 0), 47);
        int xx = min(max(px - 1, 0), 47);
        const float* src = feat + (cq * 4) * NVOX + (zz * 48 + yy) * 48 + xx;
        float4 v;
        v.x = src[0];
        v.y = src[NVOX];
        v.z = src[2 * NVOX];
        v.w = src[3 * NVOX];
        lds4[col * 9 + cq] = v;
    }
    __syncthreads();

    int tx = t & 15, ty = t >> 4;
    float4 acc[4][3];
#pragma unroll
    for (int o = 0; o < 4; ++o)
#pragma unroll
        for (int wi = 0; wi < 3; ++wi)
            acc[o][wi] = make_float4(0.f, 0.f, 0.f, 0.f);

    for (int dzdy = 0; dzdy < 9; ++dzdy) {
        int rb = dzdy * 50 + tx;
        int wbase = ty * 4 * 216 + dzdy * 24;  // float4 index into w1t
#pragma unroll
        for (int dx = 0; dx < 3; ++dx) {
#pragma unroll
            for (int cq = 0; cq < 8; ++cq) {
                float4 f0 = lds4[(rb + dx) * 9 + cq];
                float4 f1 = lds4[(rb + 16 + dx) * 9 + cq];
                float4 f2 = lds4[(rb + 32 + dx) * 9 + cq];
                float4 w0v = w1t4[wbase +       dx * 8 + cq];
                float4 w1v = w1t4[wbase + 216 + dx * 8 + cq];
                float4 w2v = w1t4[wbase + 432 + dx * 8 + cq];
                float4 w3v = w1t4[wbase + 648 + dx * 8 + cq];
                fma4(acc[0][0], w0v, f0); fma4(acc[0][1], w0v, f1); fma4(acc[0][2], w0v, f2);
                fma4(acc[1][0], w1v, f0); fma4(acc[1][1], w1v, f1); fma4(acc[1][2], w1v, f2);
                fma4(acc[2][0], w2v, f0); fma4(acc[2][1], w2v, f1); fma4(acc[2][2], w2v, f2);
                fma4(acc[3][0], w3v, f0); fma4(acc[3][1], w3v, f1); fma4(acc[3][2], w3v, f2);
            }
        }
    }

    float bl[4];
#pragma unroll
    for (int o = 0; o < 4; ++o) bl[o] = b1[ty * 4 + o];
#pragma unroll
    for (int wi = 0; wi < 3; ++wi) {
        float4 hv;
        float* hp = (float*)&hv;
#pragma unroll
        for (int o = 0; o < 4; ++o) {
            float s = acc[o][wi].x + acc[o][wi].y + acc[o][wi].z + acc[o][wi].w + bl[o];
            hp[o] = s / (1.f + __expf(-s));   // SiLU
        }
        int vox = bx * 48 + tx + wi * 16;
        ((float4*)hout)[vox * 16 + ty] = hv;  // h voxel-major [vox][64]
    }
}

// ---------------------------------------------------------------------------
// K2: conv1x1 (64->216) + softmax(27) + 27-tap convex combination + store.
// One block per 24-voxel half row.
// LDS: mbuf[8 sub][24 vox][28 pad]   (floats 0..5375)
//      xlds[234 col][36 pad]         (floats 5376..) ; hbuf[24][68] union w/ xlds
// ---------------------------------------------------------------------------
__global__ __launch_bounds__(256, 2) void k_fused(
    const float* __restrict__ x, const float* __restrict__ hws,
    const float* __restrict__ w2, const float* __restrict__ b2,
    float* __restrict__ out)
{
    __shared__ float smem[13800];            // 55.2 KB
    float4* smem4 = (float4*)smem;
    int bx = blockIdx.x;
    int d = bx / 96;
    int r = bx - d * 96;
    int hh = r >> 1;
    int w0 = (r & 1) * 24;
    int t = threadIdx.x;
    int vox0 = (d * 48 + hh) * 48 + w0;

    // A0: stage h tile [24][64] -> hbuf stride 68 (float4 idx 1344 + vox*17 + cq)
    for (int i = t; i < 384; i += 256) {
        int vox = i >> 4, cq = i & 15;
        smem4[1344 + vox * 17 + cq] = ((const float4*)hws)[(vox0 + vox) * 16 + cq];
    }
    __syncthreads();

    // A: conv2 -> mbuf  (4 mc per item, 64-ci dot products)
    const float4* w24 = (const float4*)w2;
    const float4* b24 = (const float4*)b2;
    for (int i = t; i < 1296; i += 256) {
        int mcq = i / 24;
        int vox = i - mcq * 24;
        float4 bv = b24[mcq];
        float a0 = bv.x, a1 = bv.y, a2 = bv.z, a3 = bv.w;
#pragma unroll
        for (int cq = 0; cq < 16; ++cq) {
            float4 hv = smem4[1344 + vox * 17 + cq];
            float4 v0 = w24[(mcq * 4 + 0) * 16 + cq];
            float4 v1 = w24[(mcq * 4 + 1) * 16 + cq];
            float4 v2 = w24[(mcq * 4 + 2) * 16 + cq];
            float4 v3 = w24[(mcq * 4 + 3) * 16 + cq];
            a0 = fmaf(v0.x, hv.x, fmaf(v0.y, hv.y, fmaf(v0.z, hv.z, fmaf(v0.w, hv.w, a0))));
            a1 = fmaf(v1.x, hv.x, fmaf(v1.y, hv.y, fmaf(v1.z, hv.z, fmaf(v1.w, hv.w, a1))));
            a2 = fmaf(v2.x, hv.x, fmaf(v2.y, hv.y, fmaf(v2.z, hv.z, fmaf(v2.w, hv.w, a2))));
            a3 = fmaf(v3.x, hv.x, fmaf(v3.y, hv.y, fmaf(v3.z, hv.z, fmaf(v3.w, hv.w, a3))));
        }
#pragma unroll
        for (int o = 0; o < 4; ++o) {
            int mc = mcq * 4 + o;
            int sub = mc / 27;
            int n = mc - sub * 27;
            float av = (o == 0) ? a0 : (o == 1) ? a1 : (o == 2) ? a2 : a3;
            smem[(sub * 24 + vox) * 28 + n] = av;
        }
    }
    __syncthreads();

    // stage x neighborhood (overwrites hbuf region; after sync)
    for (int i = t; i < 1872; i += 256) {
        int cq = i / 234;
        int col = i - cq * 234;
        int dzdy = col / 26;
        int px = col - dzdy * 26;
        int dz = dzdy / 3, dy = dzdy - dz * 3;
        int zz = min(max(d + dz - 1, 0), 47);
        int yy = min(max(hh + dy - 1, 0), 47);
        int xx = min(max(w0 + px - 1, 0), 47);
        const float* src = x + (cq * 4) * NVOX + (zz * 48 + yy) * 48 + xx;
        float4 v;
        v.x = src[0];
        v.y = src[NVOX];
        v.z = src[2 * NVOX];
        v.w = src[3 * NVOX];
        smem4[1344 + col * 9 + cq] = v;
    }
    // softmax over 27 taps, in place (192 independent (sub,vox) tasks)
    if (t < 192) {
        int sub = t / 24;
        int vox = t - sub * 24;
        float* p = smem + (sub * 24 + vox) * 28;
        float mx = p[0];
#pragma unroll
        for (int n = 1; n < 27; ++n) mx = fmaxf(mx, p[n]);
        float s = 0.f;
#pragma unroll
        for (int n = 0; n < 27; ++n) { float e = __expf(p[n] - mx); p[n] = e; s += e; }
        float inv = 1.f / s;
#pragma unroll
        for (int n = 0; n < 27; ++n) p[n] *= inv;
    }
    __syncthreads();

    // C: out[c][2d+i][2h+j][2w+k] = sum_n p[sub][vox][n] * x[c][nb(vox,n)]
    int tx = t & 7, ty = t >> 3;
    int cq = ty & 7, sp = ty >> 3;           // sp -> (i,j); s -> k
    float4 acc[2][3];
#pragma unroll
    for (int s = 0; s < 2; ++s)
#pragma unroll
        for (int wi = 0; wi < 3; ++wi)
            acc[s][wi] = make_float4(0.f, 0.f, 0.f, 0.f);

#pragma unroll
    for (int g = 0; g < 7; ++g) {
        float4 p4[2][3];
#pragma unroll
        for (int s = 0; s < 2; ++s)
#pragma unroll
            for (int wi = 0; wi < 3; ++wi)
                p4[s][wi] = smem4[((sp * 2 + s) * 24 + tx + wi * 8) * 7 + g];
#pragma unroll
        for (int j = 0; j < 4; ++j) {
            int n = g * 4 + j;
            if (n < 27) {
                int dz = n / 9;
                int rem = n - dz * 9;
                int dy = rem / 3, dx = rem - dy * 3;
#pragma unroll
                for (int wi = 0; wi < 3; ++wi) {
                    float4 xv = smem4[1344 + ((dz * 3 + dy) * 26 + tx + wi * 8 + dx) * 9 + cq];
                    fmas4(acc[0][wi], xv, comp4(p4[0][wi], j));
                    fmas4(acc[1][wi], xv, comp4(p4[1][wi], j));
                }
            }
        }
    }

    int i_ = sp >> 1, j_ = sp & 1;
    int rowz = 2 * d + i_;
    int rowy = 2 * hh + j_;
#pragma unroll
    for (int wi = 0; wi < 3; ++wi) {
        int wg = w0 + tx + wi * 8;
#pragma unroll
        for (int cc = 0; cc < 4; ++cc) {
            int c = cq * 4 + cc;
            float2 v;
            v.x = comp4(acc[0][wi], cc);     // k = 0
            v.y = comp4(acc[1][wi], cc);     // k = 1
            *(float2*)(out + (((size_t)c * 96 + rowz) * 96 + rowy) * 96 + 2 * wg) = v;
        }
    }
}

extern "C" void kernel_launch(void* const* d_in, const int* in_sizes, int n_in,
                              void* d_out, int out_size, void* d_ws, size_t ws_size,
                              hipStream_t stream) {
    const float* x    = (const float*)d_in[0];
    const float* feat = (const float*)d_in[1];
    const float* w1   = (const float*)d_in[2];
    const float* b1   = (const float*)d_in[3];
    const float* w2   = (const float*)d_in[4];
    const float* b2   = (const float*)d_in[5];
    float* out = (float*)d_out;

    float* w1t = (float*)d_ws;               // 55296 floats
    float* hws = w1t + 55296;                // 7,077,888 floats (h, voxel-major)

    k_w1t<<<216, 256, 0, stream>>>(w1, w1t);
    k_conv1<<<2304, 256, 0, stream>>>(feat, w1t, b1, hws);
    k_fused<<<4608, 256, 0, stream>>>(x, hws, w2, b2, out);
}

// Round 2
// 404.834 us; speedup vs baseline: 1.9074x; 1.9074x over previous
//
#include <hip/hip_runtime.h>
#include <math.h>

#define NVOX 110592   // 48*48*48

typedef _Float16 f16x8 __attribute__((ext_vector_type(8)));
typedef float    f32x4 __attribute__((ext_vector_type(4)));

__device__ __forceinline__ void fmas4(float4& a, const float4& xv, float p) {
    a.x = fmaf(xv.x, p, a.x);
    a.y = fmaf(xv.y, p, a.y);
    a.z = fmaf(xv.z, p, a.z);
    a.w = fmaf(xv.w, p, a.w);
}
__device__ __forceinline__ float comp4(const float4& v, int j) {
    return j == 0 ? v.x : (j == 1 ? v.y : (j == 2 ? v.z : v.w));
}

// ---------------------------------------------------------------------------
// K0: w1 [64 oc][32 ci][27 tap] f32  ->  w1h [64 oc][27 tap][32 ci] f16
//     (k = tap*32 + ci, matching the MFMA k-step = one tap of 32 ci)
// ---------------------------------------------------------------------------
__global__ void k_prep(const float* __restrict__ w1, _Float16* __restrict__ w1h) {
    int e = blockIdx.x * 256 + threadIdx.x;
    if (e >= 64 * 32 * 27) return;
    int oc = e / 864;
    int r = e - oc * 864;
    int ci = r / 27;
    int tap = r - ci * 27;
    w1h[oc * 864 + tap * 32 + ci] = (_Float16)w1[e];
}

// ---------------------------------------------------------------------------
// K1: conv3x3x3 (replicate pad) + SiLU via f16 MFMA 16x16x32.
// One block per (d,h) row (48 voxels). 4 waves; wave w -> oc strip w*16.
// GEMM view: A = w1h [64 oc][864 k], B = unfolded features [864 k][48 px];
// k-step = tap (32 ci). B-frags read straight from raw-staged LDS:
//   flds[dzdy 9][slot 50][ci 32] f16, slot stride 40 f16 (80 B): bank group
//   (5n+q) mod 8 -> conflict-free b128. A-frags streamed from global (L2).
// Epilogue: bias+SiLU, LDS transpose, coalesced float4 stores of h[vox][64].
// ---------------------------------------------------------------------------
__global__ __launch_bounds__(256, 4) void k_conv1(
    const float* __restrict__ feat, const _Float16* __restrict__ w1h,
    const float* __restrict__ b1, float* __restrict__ hout)
{
    __shared__ _Float16 flds[9 * 50 * 40];   // 36 KB
    int bx = blockIdx.x;
    int d = bx / 48, hh = bx - d * 48;
    int t = threadIdx.x;

    // stage features f32 -> f16 (replicate-clamped), coalesced along px
    for (int i = t; i < 3600; i += 256) {
        int o = i / 450;                     // ci group of 4 (0..7)
        int col = i - o * 450;               // dzdy*50 + slot
        int dzdy = col / 50;
        int px = col - dzdy * 50;
        int dz = dzdy / 3, dy = dzdy - dz * 3;
        int zz = min(max(d + dz - 1, 0), 47);
        int yy = min(max(hh + dy - 1, 0), 47);
        int xx = min(max(px - 1, 0), 47);
        const float* src = feat + (o * 4) * NVOX + (zz * 48 + yy) * 48 + xx;
        _Float16* dst = flds + col * 40 + o * 4;
        dst[0] = (_Float16)src[0];
        dst[1] = (_Float16)src[NVOX];
        dst[2] = (_Float16)src[2 * NVOX];
        dst[3] = (_Float16)src[3 * NVOX];
    }
    __syncthreads();

    int wid = t >> 6;                        // 0..3 -> oc strip
    int lane = t & 63;
    int mcol = lane & 15;                    // A row (oc) / B col (px)
    int q = lane >> 4;                       // quad: k = q*8 + j

    const _Float16* wbase = w1h + (wid * 16 + mcol) * 864 + q * 8;

    f32x4 acc0 = {0.f, 0.f, 0.f, 0.f};
    f32x4 acc1 = {0.f, 0.f, 0.f, 0.f};
    f32x4 acc2 = {0.f, 0.f, 0.f, 0.f};

#pragma unroll 3
    for (int dzdy = 0; dzdy < 9; ++dzdy) {
        const _Float16* brow = flds + (dzdy * 50 + mcol) * 40 + q * 8;
        const _Float16* wrow = wbase + dzdy * 96;     // 3 taps * 32
#pragma unroll
        for (int dx = 0; dx < 3; ++dx) {
            f16x8 av = *(const f16x8*)(wrow + dx * 32);
            const _Float16* bb = brow + dx * 40;
            f16x8 b0 = *(const f16x8*)(bb);
            f16x8 b1v = *(const f16x8*)(bb + 16 * 40);
            f16x8 b2v = *(const f16x8*)(bb + 32 * 40);
            acc0 = __builtin_amdgcn_mfma_f32_16x16x32_f16(av, b0, acc0, 0, 0, 0);
            acc1 = __builtin_amdgcn_mfma_f32_16x16x32_f16(av, b1v, acc1, 0, 0, 0);
            acc2 = __builtin_amdgcn_mfma_f32_16x16x32_f16(av, b2v, acc2, 0, 0, 0);
        }
    }

    // epilogue: bias + SiLU, transpose via LDS, coalesced store
    __syncthreads();                          // features no longer needed
    float* trans = (float*)flds;              // [48 px][68 oc-stride] = 13 KB
    float4 bv = ((const float4*)b1)[wid * 4 + q];
    {
        f32x4 accs[3] = {acc0, acc1, acc2};
#pragma unroll
        for (int p = 0; p < 3; ++p) {
            int px = p * 16 + mcol;           // D: col = lane&15
            float4 o;
            float s;
            s = accs[p][0] + bv.x; o.x = s / (1.f + __expf(-s));
            s = accs[p][1] + bv.y; o.y = s / (1.f + __expf(-s));
            s = accs[p][2] + bv.z; o.z = s / (1.f + __expf(-s));
            s = accs[p][3] + bv.w; o.w = s / (1.f + __expf(-s));
            *(float4*)(trans + px * 68 + wid * 16 + q * 4) = o;  // row = q*4+reg
        }
    }
    __syncthreads();
    for (int i = t; i < 768; i += 256) {
        int cq = i & 15, px = i >> 4;
        float4 v = *(const float4*)(trans + px * 68 + cq * 4);
        ((float4*)hout)[(bx * 48 + px) * 16 + cq] = v;
    }
}

// ---------------------------------------------------------------------------
// K2: conv1x1 (64->216) + softmax(27) + 27-tap convex combination + store.
// One block per 24-voxel half row.  (unchanged this round)
// ---------------------------------------------------------------------------
__global__ __launch_bounds__(256, 2) void k_fused(
    const float* __restrict__ x, const float* __restrict__ hws,
    const float* __restrict__ w2, const float* __restrict__ b2,
    float* __restrict__ out)
{
    __shared__ float smem[13800];            // 55.2 KB
    float4* smem4 = (float4*)smem;
    int bx = blockIdx.x;
    int d = bx / 96;
    int r = bx - d * 96;
    int hh = r >> 1;
    int w0 = (r & 1) * 24;
    int t = threadIdx.x;
    int vox0 = (d * 48 + hh) * 48 + w0;

    // A0: stage h tile [24][64] -> hbuf stride 68 (float4 idx 1344 + vox*17 + cq)
    for (int i = t; i < 384; i += 256) {
        int vox = i >> 4, cq = i & 15;
        smem4[1344 + vox * 17 + cq] = ((const float4*)hws)[(vox0 + vox) * 16 + cq];
    }
    __syncthreads();

    // A: conv2 -> mbuf  (4 mc per item, 64-ci dot products)
    const float4* w24 = (const float4*)w2;
    const float4* b24 = (const float4*)b2;
    for (int i = t; i < 1296; i += 256) {
        int mcq = i / 24;
        int vox = i - mcq * 24;
        float4 bv = b24[mcq];
        float a0 = bv.x, a1 = bv.y, a2 = bv.z, a3 = bv.w;
#pragma unroll
        for (int cq = 0; cq < 16; ++cq) {
            float4 hv = smem4[1344 + vox * 17 + cq];
            float4 v0 = w24[(mcq * 4 + 0) * 16 + cq];
            float4 v1 = w24[(mcq * 4 + 1) * 16 + cq];
            float4 v2 = w24[(mcq * 4 + 2) * 16 + cq];
            float4 v3 = w24[(mcq * 4 + 3) * 16 + cq];
            a0 = fmaf(v0.x, hv.x, fmaf(v0.y, hv.y, fmaf(v0.z, hv.z, fmaf(v0.w, hv.w, a0))));
            a1 = fmaf(v1.x, hv.x, fmaf(v1.y, hv.y, fmaf(v1.z, hv.z, fmaf(v1.w, hv.w, a1))));
            a2 = fmaf(v2.x, hv.x, fmaf(v2.y, hv.y, fmaf(v2.z, hv.z, fmaf(v2.w, hv.w, a2))));
            a3 = fmaf(v3.x, hv.x, fmaf(v3.y, hv.y, fmaf(v3.z, hv.z, fmaf(v3.w, hv.w, a3))));
        }
#pragma unroll
        for (int o = 0; o < 4; ++o) {
            int mc = mcq * 4 + o;
            int sub = mc / 27;
            int n = mc - sub * 27;
            float av = (o == 0) ? a0 : (o == 1) ? a1 : (o == 2) ? a2 : a3;
            smem[(sub * 24 + vox) * 28 + n] = av;
        }
    }
    __syncthreads();

    // stage x neighborhood (overwrites hbuf region; after sync)
    for (int i = t; i < 1872; i += 256) {
        int cq = i / 234;
        int col = i - cq * 234;
        int dzdy = col / 26;
        int px = col - dzdy * 26;
        int dz = dzdy / 3, dy = dzdy - dz * 3;
        int zz = min(max(d + dz - 1, 0), 47);
        int yy = min(max(hh + dy - 1, 0), 47);
        int xx = min(max(w0 + px - 1, 0), 47);
        const float* src = x + (cq * 4) * NVOX + (zz * 48 + yy) * 48 + xx;
        float4 v;
        v.x = src[0];
        v.y = src[NVOX];
        v.z = src[2 * NVOX];
        v.w = src[3 * NVOX];
        smem4[1344 + col * 9 + cq] = v;
    }
    // softmax over 27 taps, in place (192 independent (sub,vox) tasks)
    if (t < 192) {
        int sub = t / 24;
        int vox = t - sub * 24;
        float* p = smem + (sub * 24 + vox) * 28;
        float mx = p[0];
#pragma unroll
        for (int n = 1; n < 27; ++n) mx = fmaxf(mx, p[n]);
        float s = 0.f;
#pragma unroll
        for (int n = 0; n < 27; ++n) { float e = __expf(p[n] - mx); p[n] = e; s += e; }
        float inv = 1.f / s;
#pragma unroll
        for (int n = 0; n < 27; ++n) p[n] *= inv;
    }
    __syncthreads();

    // C: out[c][2d+i][2h+j][2w+k] = sum_n p[sub][vox][n] * x[c][nb(vox,n)]
    int tx = t & 7, ty = t >> 3;
    int cq = ty & 7, sp = ty >> 3;           // sp -> (i,j); s -> k
    float4 acc[2][3];
#pragma unroll
    for (int s = 0; s < 2; ++s)
#pragma unroll
        for (int wi = 0; wi < 3; ++wi)
            acc[s][wi] = make_float4(0.f, 0.f, 0.f, 0.f);

#pragma unroll
    for (int g = 0; g < 7; ++g) {
        float4 p4[2][3];
#pragma unroll
        for (int s = 0; s < 2; ++s)
#pragma unroll
            for (int wi = 0; wi < 3; ++wi)
                p4[s][wi] = smem4[((sp * 2 + s) * 24 + tx + wi * 8) * 7 + g];
#pragma unroll
        for (int j = 0; j < 4; ++j) {
            int n = g * 4 + j;
            if (n < 27) {
                int dz = n / 9;
                int rem = n - dz * 9;
                int dy = rem / 3, dx = rem - dy * 3;
#pragma unroll
                for (int wi = 0; wi < 3; ++wi) {
                    float4 xv = smem4[1344 + ((dz * 3 + dy) * 26 + tx + wi * 8 + dx) * 9 + cq];
                    fmas4(acc[0][wi], xv, comp4(p4[0][wi], j));
                    fmas4(acc[1][wi], xv, comp4(p4[1][wi], j));
                }
            }
        }
    }

    int i_ = sp >> 1, j_ = sp & 1;
    int rowz = 2 * d + i_;
    int rowy = 2 * hh + j_;
#pragma unroll
    for (int wi = 0; wi < 3; ++wi) {
        int wg = w0 + tx + wi * 8;
#pragma unroll
        for (int cc = 0; cc < 4; ++cc) {
            int c = cq * 4 + cc;
            float2 v;
            v.x = comp4(acc[0][wi], cc);     // k = 0
            v.y = comp4(acc[1][wi], cc);     // k = 1
            *(float2*)(out + (((size_t)c * 96 + rowz) * 96 + rowy) * 96 + 2 * wg) = v;
        }
    }
}

extern "C" void kernel_launch(void* const* d_in, const int* in_sizes, int n_in,
                              void* d_out, int out_size, void* d_ws, size_t ws_size,
                              hipStream_t stream) {
    const float* x    = (const float*)d_in[0];
    const float* feat = (const float*)d_in[1];
    const float* w1   = (const float*)d_in[2];
    const float* b1   = (const float*)d_in[3];
    const float* w2   = (const float*)d_in[4];
    const float* b2   = (const float*)d_in[5];
    float* out = (float*)d_out;

    _Float16* w1h = (_Float16*)d_ws;                     // 55296 f16 = 110592 B
    float* hws = (float*)((char*)d_ws + 110592);         // 7,077,888 floats

    k_prep<<<216, 256, 0, stream>>>(w1, w1h);
    k_conv1<<<2304, 256, 0, stream>>>(feat, w1h, b1, hws);
    k_fused<<<4608, 256, 0, stream>>>(x, hws, w2, b2, out);
}

// Round 3
// 285.147 us; speedup vs baseline: 2.7080x; 1.4197x over previous
//
#include <hip/hip_runtime.h>
#include <math.h>

#define NVOX 110592   // 48*48*48

typedef _Float16 f16x8 __attribute__((ext_vector_type(8)));
typedef _Float16 f16x4 __attribute__((ext_vector_type(4)));
typedef float    f32x4 __attribute__((ext_vector_type(4)));

__device__ __forceinline__ void fmas4(float4& a, const float4& xv, float p) {
    a.x = fmaf(xv.x, p, a.x);
    a.y = fmaf(xv.y, p, a.y);
    a.z = fmaf(xv.z, p, a.z);
    a.w = fmaf(xv.w, p, a.w);
}
__device__ __forceinline__ float comp4(const float4& v, int j) {
    return j == 0 ? v.x : (j == 1 ? v.y : (j == 2 ? v.z : v.w));
}

// ---------------------------------------------------------------------------
// K0: prep weights.
//  w1 [64 oc][32 ci][27 tap] f32 -> w1h [64 oc][27 tap][32 ci] f16
//  w2 [216 oc][64 ci] f32       -> w2h [224 oc][64 ci] f16 (rows 216.. zero)
// ---------------------------------------------------------------------------
__global__ void k_prep(const float* __restrict__ w1, const float* __restrict__ w2,
                       _Float16* __restrict__ w1h, _Float16* __restrict__ w2h) {
    int e = blockIdx.x * 256 + threadIdx.x;
    if (e < 64 * 32 * 27) {
        int oc = e / 864;
        int r = e - oc * 864;
        int ci = r / 27;
        int tap = r - ci * 27;
        w1h[oc * 864 + tap * 32 + ci] = (_Float16)w1[e];
    }
    int e2 = e - 55296;
    if (e2 >= 0 && e2 < 224 * 64) {
        int oc = e2 >> 6, k = e2 & 63;
        w2h[e2] = (oc < 216) ? (_Float16)w2[oc * 64 + k] : (_Float16)0.f;
    }
}

// ---------------------------------------------------------------------------
// K1: conv3x3x3 (replicate pad) + SiLU via f16 MFMA 16x16x32.
// One block per (d,h) row (48 voxels). 4 waves; wave w -> oc strip w*16.
// B-frags read from raw-staged LDS flds[dzdy 9][slot 50][ci 32] f16,
// slot stride 40 f16 -> conflict-free. Output h as f16 [vox][64].
// ---------------------------------------------------------------------------
__global__ __launch_bounds__(256, 4) void k_conv1(
    const float* __restrict__ feat, const _Float16* __restrict__ w1h,
    const float* __restrict__ b1, _Float16* __restrict__ hout)
{
    __shared__ _Float16 flds[9 * 50 * 40];   // 36 KB
    int bx = blockIdx.x;
    int d = bx / 48, hh = bx - d * 48;
    int t = threadIdx.x;

    // stage features f32 -> f16 (replicate-clamped), coalesced along px
    for (int i = t; i < 3600; i += 256) {
        int o = i / 450;                     // ci group of 4 (0..7)
        int col = i - o * 450;               // dzdy*50 + slot
        int dzdy = col / 50;
        int px = col - dzdy * 50;
        int dz = dzdy / 3, dy = dzdy - dz * 3;
        int zz = min(max(d + dz - 1, 0), 47);
        int yy = min(max(hh + dy - 1, 0), 47);
        int xx = min(max(px - 1, 0), 47);
        const float* src = feat + (o * 4) * NVOX + (zz * 48 + yy) * 48 + xx;
        _Float16* dst = flds + col * 40 + o * 4;
        dst[0] = (_Float16)src[0];
        dst[1] = (_Float16)src[NVOX];
        dst[2] = (_Float16)src[2 * NVOX];
        dst[3] = (_Float16)src[3 * NVOX];
    }
    __syncthreads();

    int wid = t >> 6;                        // 0..3 -> oc strip
    int lane = t & 63;
    int mcol = lane & 15;                    // A row (oc) / B col (px)
    int q = lane >> 4;                       // quad: k = q*8 + j

    const _Float16* wbase = w1h + (wid * 16 + mcol) * 864 + q * 8;

    f32x4 acc0 = {0.f, 0.f, 0.f, 0.f};
    f32x4 acc1 = {0.f, 0.f, 0.f, 0.f};
    f32x4 acc2 = {0.f, 0.f, 0.f, 0.f};

#pragma unroll 3
    for (int dzdy = 0; dzdy < 9; ++dzdy) {
        const _Float16* brow = flds + (dzdy * 50 + mcol) * 40 + q * 8;
        const _Float16* wrow = wbase + dzdy * 96;     // 3 taps * 32
#pragma unroll
        for (int dx = 0; dx < 3; ++dx) {
            f16x8 av = *(const f16x8*)(wrow + dx * 32);
            const _Float16* bb = brow + dx * 40;
            f16x8 b0 = *(const f16x8*)(bb);
            f16x8 b1v = *(const f16x8*)(bb + 16 * 40);
            f16x8 b2v = *(const f16x8*)(bb + 32 * 40);
            acc0 = __builtin_amdgcn_mfma_f32_16x16x32_f16(av, b0, acc0, 0, 0, 0);
            acc1 = __builtin_amdgcn_mfma_f32_16x16x32_f16(av, b1v, acc1, 0, 0, 0);
            acc2 = __builtin_amdgcn_mfma_f32_16x16x32_f16(av, b2v, acc2, 0, 0, 0);
        }
    }

    // epilogue: bias + SiLU -> f16, transpose via LDS, coalesced f16x8 store
    __syncthreads();                          // features no longer needed
    _Float16* transh = flds;                  // [48 px][72 ch-stride] f16
    float4 bv = ((const float4*)b1)[wid * 4 + q];
    {
        f32x4 accs[3] = {acc0, acc1, acc2};
#pragma unroll
        for (int p = 0; p < 3; ++p) {
            int px = p * 16 + mcol;           // D: col = lane&15
            f16x4 o;
            float s;
            s = accs[p][0] + bv.x; o.x = (_Float16)(s / (1.f + __expf(-s)));
            s = accs[p][1] + bv.y; o.y = (_Float16)(s / (1.f + __expf(-s)));
            s = accs[p][2] + bv.z; o.z = (_Float16)(s / (1.f + __expf(-s)));
            s = accs[p][3] + bv.w; o.w = (_Float16)(s / (1.f + __expf(-s)));
            *(f16x4*)(transh + px * 72 + wid * 16 + q * 4) = o;  // row = q*4+reg
        }
    }
    __syncthreads();
    for (int i = t; i < 384; i += 256) {
        int c = i & 7, px = i >> 3;
        f16x8 v = *(const f16x8*)(transh + px * 72 + c * 8);
        ((f16x8*)hout)[(bx * 48 + px) * 8 + c] = v;
    }
}

// ---------------------------------------------------------------------------
// K2: conv1x1 (64->216) via f16 MFMA + softmax(27) + 27-tap combination.
// One block per 24-voxel half row (padded to 32 for N-tiles of 16).
// LDS: mbuf[8 sub][24 vox][28 pad] f32 (floats 0..5375)
//      x region floats 5376..13799 ([234 col][36]); h f16 tile aliases it.
// ---------------------------------------------------------------------------
__global__ __launch_bounds__(256, 2) void k_fused(
    const float* __restrict__ x, const _Float16* __restrict__ hws,
    const _Float16* __restrict__ w2h, const float* __restrict__ b2,
    float* __restrict__ out)
{
    __shared__ float smem[13800];            // 55.2 KB
    float4* smem4 = (float4*)smem;
    _Float16* hl = (_Float16*)(smem + 5376); // [32 vox][72] f16 (aliases x region)
    int bx = blockIdx.x;
    int d = bx / 96;
    int r = bx - d * 96;
    int hh = r >> 1;
    int w0 = (r & 1) * 24;
    int t = threadIdx.x;
    int vox0 = (d * 48 + hh) * 48 + w0;

    // stage h tile [24][64] f16 -> stride 72; zero-pad vox 24..31
    if (t < 192) {
        int vox = t >> 3, c = t & 7;
        *(f16x8*)(hl + vox * 72 + c * 8) = ((const f16x8*)hws)[(vox0 + vox) * 8 + c];
    } else {
        int i = t - 192;
        int vox = 24 + (i >> 3), c = i & 7;
        f16x8 z = {0, 0, 0, 0, 0, 0, 0, 0};
        *(f16x8*)(hl + vox * 72 + c * 8) = z;
    }
    __syncthreads();

    // conv2 via MFMA: A = w2h [224][64], B = h tile. Wave w: M-tiles w,w+4,w+8,w+12
    {
        int wid = t >> 6, lane = t & 63;
        int mcol = lane & 15, q = lane >> 4;
        for (int mt = wid; mt < 14; mt += 4) {
            float bias[4];
#pragma unroll
            for (int rr = 0; rr < 4; ++rr) {
                int oc = mt * 16 + q * 4 + rr;
                bias[rr] = (oc < 216) ? b2[oc] : 0.f;
            }
            f32x4 acc0 = {bias[0], bias[1], bias[2], bias[3]};
            f32x4 acc1 = acc0;
#pragma unroll
            for (int ks = 0; ks < 2; ++ks) {
                f16x8 av = *(const f16x8*)(w2h + (mt * 16 + mcol) * 64 + ks * 32 + q * 8);
                f16x8 bv0 = *(const f16x8*)(hl + mcol * 72 + ks * 32 + q * 8);
                f16x8 bv1 = *(const f16x8*)(hl + (16 + mcol) * 72 + ks * 32 + q * 8);
                acc0 = __builtin_amdgcn_mfma_f32_16x16x32_f16(av, bv0, acc0, 0, 0, 0);
                acc1 = __builtin_amdgcn_mfma_f32_16x16x32_f16(av, bv1, acc1, 0, 0, 0);
            }
            // scatter C frags into m[sub][vox][28]
#pragma unroll
            for (int rr = 0; rr < 4; ++rr) {
                int oc = mt * 16 + q * 4 + rr;
                if (oc < 216) {
                    int sub = oc / 27;
                    int n = oc - sub * 27;
                    smem[(sub * 24 + mcol) * 28 + n] = acc0[rr];
                    int vox1 = 16 + mcol;
                    if (vox1 < 24)
                        smem[(sub * 24 + vox1) * 28 + n] = acc1[rr];
                }
            }
        }
    }
    __syncthreads();

    // stage x neighborhood (overwrites h region; after sync)
    for (int i = t; i < 1872; i += 256) {
        int cq = i / 234;
        int col = i - cq * 234;
        int dzdy = col / 26;
        int px = col - dzdy * 26;
        int dz = dzdy / 3, dy = dzdy - dz * 3;
        int zz = min(max(d + dz - 1, 0), 47);
        int yy = min(max(hh + dy - 1, 0), 47);
        int xx = min(max(w0 + px - 1, 0), 47);
        const float* src = x + (cq * 4) * NVOX + (zz * 48 + yy) * 48 + xx;
        float4 v;
        v.x = src[0];
        v.y = src[NVOX];
        v.z = src[2 * NVOX];
        v.w = src[3 * NVOX];
        smem4[1344 + col * 9 + cq] = v;
    }
    // softmax over 27 taps, in place (192 independent (sub,vox) tasks)
    if (t < 192) {
        int sub = t / 24;
        int vox = t - sub * 24;
        float* p = smem + (sub * 24 + vox) * 28;
        float mx = p[0];
#pragma unroll
        for (int n = 1; n < 27; ++n) mx = fmaxf(mx, p[n]);
        float s = 0.f;
#pragma unroll
        for (int n = 0; n < 27; ++n) { float e = __expf(p[n] - mx); p[n] = e; s += e; }
        float inv = 1.f / s;
#pragma unroll
        for (int n = 0; n < 27; ++n) p[n] *= inv;
    }
    __syncthreads();

    // C: out[c][2d+i][2h+j][2w+k] = sum_n p[sub][vox][n] * x[c][nb(vox,n)]
    int tx = t & 7, ty = t >> 3;
    int cq = ty & 7, sp = ty >> 3;           // sp -> (i,j)
    float4 acc[2][3];
#pragma unroll
    for (int s = 0; s < 2; ++s)
#pragma unroll
        for (int wi = 0; wi < 3; ++wi)
            acc[s][wi] = make_float4(0.f, 0.f, 0.f, 0.f);

#pragma unroll
    for (int g = 0; g < 7; ++g) {
        float4 p4[2][3];
#pragma unroll
        for (int s = 0; s < 2; ++s)
#pragma unroll
            for (int wi = 0; wi < 3; ++wi)
                p4[s][wi] = smem4[((sp * 2 + s) * 24 + tx + wi * 8) * 7 + g];
#pragma unroll
        for (int j = 0; j < 4; ++j) {
            int n = g * 4 + j;
            if (n < 27) {
                int dz = n / 9;
                int rem = n - dz * 9;
                int dy = rem / 3, dx = rem - dy * 3;
#pragma unroll
                for (int wi = 0; wi < 3; ++wi) {
                    float4 xv = smem4[1344 + ((dz * 3 + dy) * 26 + tx + wi * 8 + dx) * 9 + cq];
                    fmas4(acc[0][wi], xv, comp4(p4[0][wi], j));
                    fmas4(acc[1][wi], xv, comp4(p4[1][wi], j));
                }
            }
        }
    }

    int i_ = sp >> 1, j_ = sp & 1;
    int rowz = 2 * d + i_;
    int rowy = 2 * hh + j_;
#pragma unroll
    for (int wi = 0; wi < 3; ++wi) {
        int wg = w0 + tx + wi * 8;
#pragma unroll
        for (int cc = 0; cc < 4; ++cc) {
            int c = cq * 4 + cc;
            float2 v;
            v.x = comp4(acc[0][wi], cc);     // k = 0
            v.y = comp4(acc[1][wi], cc);     // k = 1
            *(float2*)(out + (((size_t)c * 96 + rowz) * 96 + rowy) * 96 + 2 * wg) = v;
        }
    }
}

extern "C" void kernel_launch(void* const* d_in, const int* in_sizes, int n_in,
                              void* d_out, int out_size, void* d_ws, size_t ws_size,
                              hipStream_t stream) {
    const float* x    = (const float*)d_in[0];
    const float* feat = (const float*)d_in[1];
    const float* w1   = (const float*)d_in[2];
    const float* b1   = (const float*)d_in[3];
    const float* w2   = (const float*)d_in[4];
    const float* b2   = (const float*)d_in[5];
    float* out = (float*)d_out;

    _Float16* w1h = (_Float16*)d_ws;                         // 110592 B
    _Float16* w2h = (_Float16*)((char*)d_ws + 110592);       //  28672 B
    _Float16* hws = (_Float16*)((char*)d_ws + 139264);       // 14.2 MB

    k_prep<<<272, 256, 0, stream>>>(w1, w2, w1h, w2h);
    k_conv1<<<2304, 256, 0, stream>>>(feat, w1h, b1, hws);
    k_fused<<<4608, 256, 0, stream>>>(x, hws, w2h, b2, out);
}

// Round 4
// 262.134 us; speedup vs baseline: 2.9457x; 1.0878x over previous
//
#include <hip/hip_runtime.h>
#include <math.h>

#define NVOX 110592   // 48*48*48

typedef _Float16 f16x8 __attribute__((ext_vector_type(8)));
typedef _Float16 f16x4 __attribute__((ext_vector_type(4)));
typedef _Float16 f16x2 __attribute__((ext_vector_type(2)));
typedef float    f32x4 __attribute__((ext_vector_type(4)));

__device__ __forceinline__ void fmas4(float4& a, const float4& xv, float p) {
    a.x = fmaf(xv.x, p, a.x);
    a.y = fmaf(xv.y, p, a.y);
    a.z = fmaf(xv.z, p, a.z);
    a.w = fmaf(xv.w, p, a.w);
}
__device__ __forceinline__ float comp4(const float4& v, int j) {
    return j == 0 ? v.x : (j == 1 ? v.y : (j == 2 ? v.z : v.w));
}

// ---------------------------------------------------------------------------
// K0a: weights.
//  w1 [64 oc][32 ci][27 tap] f32 -> w1h [64 oc][27 tap][32 ci] f16
//  w2 [216 oc][64 ci] f32       -> w2h [224 oc][64 ci] f16 (rows 216.. zero)
// ---------------------------------------------------------------------------
__global__ void k_prep(const float* __restrict__ w1, const float* __restrict__ w2,
                       _Float16* __restrict__ w1h, _Float16* __restrict__ w2h) {
    int e = blockIdx.x * 256 + threadIdx.x;
    if (e < 64 * 32 * 27) {
        int oc = e / 864;
        int r = e - oc * 864;
        int ci = r / 27;
        int tap = r - ci * 27;
        w1h[oc * 864 + tap * 32 + ci] = (_Float16)w1[e];
    }
    int e2 = e - 55296;
    if (e2 >= 0 && e2 < 224 * 64) {
        int oc = e2 >> 6, k = e2 & 63;
        w2h[e2] = (oc < 216) ? (_Float16)w2[oc * 64 + k] : (_Float16)0.f;
    }
}

// ---------------------------------------------------------------------------
// K0b: transpose+cast feat and x: [32 c][NVOX] f32 -> [NVOX][32 c] f16.
// Block = 64 voxels. Phase1: coalesced c-plane reads -> LDS tile (f16x2
// writes, stride 36 f16 -> ~4-way max). Phase2: b64 LDS reads -> fully
// coalesced 16B-chunk global writes.
// ---------------------------------------------------------------------------
__global__ __launch_bounds__(256) void k_prepT(
    const float* __restrict__ feat, const float* __restrict__ x,
    _Float16* __restrict__ featT, _Float16* __restrict__ xT)
{
    __shared__ _Float16 tile[64 * 36];
    int bx = blockIdx.x;
    int which = bx >= 1728;
    int v0 = (which ? bx - 1728 : bx) * 64;
    const float* s = which ? x : feat;
    _Float16* dt = which ? xT : featT;
    int t = threadIdx.x;

    for (int i = t; i < 1024; i += 256) {
        int c2 = i >> 6, dv = i & 63;
        f16x2 v;
        v.x = (_Float16)s[(2 * c2) * NVOX + v0 + dv];
        v.y = (_Float16)s[(2 * c2 + 1) * NVOX + v0 + dv];
        *(f16x2*)(tile + dv * 36 + c2 * 2) = v;
    }
    __syncthreads();
    for (int i = t; i < 512; i += 256) {
        int dv = i >> 3, ch = i & 7;
        f16x4 v = *(const f16x4*)(tile + dv * 36 + ch * 4);
        *(f16x4*)(dt + (v0 + dv) * 32 + ch * 4) = v;
    }
}

// ---------------------------------------------------------------------------
// K1: conv3x3x3 (replicate pad) + SiLU via f16 MFMA 16x16x32.
// One block per (d,h) row (48 voxels). 4 waves; wave w -> oc strip w*16.
// Staging is now pure b128 copies from featT[vox][32]: item = (col, chunk),
// chunk-fast lanes -> bank-uniform LDS writes, perfectly coalesced reads.
// flds[col 450][40 f16 stride] -> conflict-free MFMA B-frag b128 reads.
// ---------------------------------------------------------------------------
__global__ __launch_bounds__(256, 4) void k_conv1(
    const _Float16* __restrict__ featT, const _Float16* __restrict__ w1h,
    const float* __restrict__ b1, _Float16* __restrict__ hout)
{
    __shared__ _Float16 flds[450 * 40];      // 36 KB
    int bx = blockIdx.x;
    int d = bx / 48, hh = bx - d * 48;
    int t = threadIdx.x;

    for (int i = t; i < 1800; i += 256) {
        int col = i >> 2, chunk = i & 3;     // col = dzdy*50 + px
        int dzdy = col / 50;
        int px = col - dzdy * 50;
        int dz = dzdy / 3, dy = dzdy - dz * 3;
        int zz = min(max(d + dz - 1, 0), 47);
        int yy = min(max(hh + dy - 1, 0), 47);
        int xx = min(max(px - 1, 0), 47);
        int vox = (zz * 48 + yy) * 48 + xx;
        *(f16x8*)(flds + col * 40 + chunk * 8) =
            *(const f16x8*)(featT + vox * 32 + chunk * 8);
    }
    __syncthreads();

    int wid = t >> 6;                        // 0..3 -> oc strip
    int lane = t & 63;
    int mcol = lane & 15;                    // A row (oc) / B col (px)
    int q = lane >> 4;                       // quad: k = q*8 + j

    const _Float16* wbase = w1h + (wid * 16 + mcol) * 864 + q * 8;

    f32x4 acc0 = {0.f, 0.f, 0.f, 0.f};
    f32x4 acc1 = {0.f, 0.f, 0.f, 0.f};
    f32x4 acc2 = {0.f, 0.f, 0.f, 0.f};

#pragma unroll 3
    for (int dzdy = 0; dzdy < 9; ++dzdy) {
        const _Float16* brow = flds + (dzdy * 50 + mcol) * 40 + q * 8;
        const _Float16* wrow = wbase + dzdy * 96;     // 3 taps * 32
#pragma unroll
        for (int dx = 0; dx < 3; ++dx) {
            f16x8 av = *(const f16x8*)(wrow + dx * 32);
            const _Float16* bb = brow + dx * 40;
            f16x8 b0 = *(const f16x8*)(bb);
            f16x8 b1v = *(const f16x8*)(bb + 16 * 40);
            f16x8 b2v = *(const f16x8*)(bb + 32 * 40);
            acc0 = __builtin_amdgcn_mfma_f32_16x16x32_f16(av, b0, acc0, 0, 0, 0);
            acc1 = __builtin_amdgcn_mfma_f32_16x16x32_f16(av, b1v, acc1, 0, 0, 0);
            acc2 = __builtin_amdgcn_mfma_f32_16x16x32_f16(av, b2v, acc2, 0, 0, 0);
        }
    }

    // epilogue: bias + SiLU -> f16, transpose via LDS, coalesced f16x8 store
    __syncthreads();
    _Float16* transh = flds;                  // [48 px][72 f16 stride]
    float4 bv = ((const float4*)b1)[wid * 4 + q];
    {
        f32x4 accs[3] = {acc0, acc1, acc2};
#pragma unroll
        for (int p = 0; p < 3; ++p) {
            int px = p * 16 + mcol;           // D: col = lane&15
            f16x4 o;
            float s;
            s = accs[p][0] + bv.x; o.x = (_Float16)(s / (1.f + __expf(-s)));
            s = accs[p][1] + bv.y; o.y = (_Float16)(s / (1.f + __expf(-s)));
            s = accs[p][2] + bv.z; o.z = (_Float16)(s / (1.f + __expf(-s)));
            s = accs[p][3] + bv.w; o.w = (_Float16)(s / (1.f + __expf(-s)));
            *(f16x4*)(transh + px * 72 + wid * 16 + q * 4) = o;  // row = q*4+reg
        }
    }
    __syncthreads();
    for (int i = t; i < 384; i += 256) {
        int c = i & 7, px = i >> 3;
        f16x8 v = *(const f16x8*)(transh + px * 72 + c * 8);
        ((f16x8*)hout)[(bx * 48 + px) * 8 + c] = v;
    }
}

// ---------------------------------------------------------------------------
// K2: conv1x1 (64->216) via f16 MFMA + softmax(27) + 27-tap combination.
// One block per 24-voxel half row.  LDS 39.3 KB -> 4 blocks/CU:
//   mbuf [8 sub][24 vox][28 pad] f32   floats [0, 5376)
//   xh   [234 col][40 f16 stride] f16  floats [5376, 10056); h tile aliases.
// x staged as pure b128 copies from xT[vox][32] f16 (bank-uniform).
// Softmax vectorized (7 b128 reads + 7 writes per row).
// ---------------------------------------------------------------------------
__global__ __launch_bounds__(256, 4) void k_fused(
    const _Float16* __restrict__ xT, const _Float16* __restrict__ hws,
    const _Float16* __restrict__ w2h, const float* __restrict__ b2,
    float* __restrict__ out)
{
    __shared__ float smem[10056];            // 40.2 KB
    _Float16* hl = (_Float16*)(smem + 5376); // [32 vox][72] f16 (aliases xh)
    _Float16* xh = (_Float16*)(smem + 5376); // [234 col][40] f16
    int bx = blockIdx.x;
    int d = bx / 96;
    int r = bx - d * 96;
    int hh = r >> 1;
    int w0 = (r & 1) * 24;
    int t = threadIdx.x;
    int vox0 = (d * 48 + hh) * 48 + w0;

    // stage h tile [24][64] f16 -> stride 72; zero-pad vox 24..31
    if (t < 192) {
        int vox = t >> 3, c = t & 7;
        *(f16x8*)(hl + vox * 72 + c * 8) = ((const f16x8*)hws)[(vox0 + vox) * 8 + c];
    } else {
        int i = t - 192;
        int vox = 24 + (i >> 3), c = i & 7;
        f16x8 z = {0, 0, 0, 0, 0, 0, 0, 0};
        *(f16x8*)(hl + vox * 72 + c * 8) = z;
    }
    __syncthreads();

    // conv2 via MFMA: A = w2h [224][64], B = h tile. Wave w: M-tiles w,w+4,w+8,w+12
    {
        int wid = t >> 6, lane = t & 63;
        int mcol = lane & 15, q = lane >> 4;
        for (int mt = wid; mt < 14; mt += 4) {
            float bias[4];
#pragma unroll
            for (int rr = 0; rr < 4; ++rr) {
                int oc = mt * 16 + q * 4 + rr;
                bias[rr] = (oc < 216) ? b2[oc] : 0.f;
            }
            f32x4 acc0 = {bias[0], bias[1], bias[2], bias[3]};
            f32x4 acc1 = acc0;
#pragma unroll
            for (int ks = 0; ks < 2; ++ks) {
                f16x8 av = *(const f16x8*)(w2h + (mt * 16 + mcol) * 64 + ks * 32 + q * 8);
                f16x8 bv0 = *(const f16x8*)(hl + mcol * 72 + ks * 32 + q * 8);
                f16x8 bv1 = *(const f16x8*)(hl + (16 + mcol) * 72 + ks * 32 + q * 8);
                acc0 = __builtin_amdgcn_mfma_f32_16x16x32_f16(av, bv0, acc0, 0, 0, 0);
                acc1 = __builtin_amdgcn_mfma_f32_16x16x32_f16(av, bv1, acc1, 0, 0, 0);
            }
#pragma unroll
            for (int rr = 0; rr < 4; ++rr) {
                int oc = mt * 16 + q * 4 + rr;
                if (oc < 216) {
                    int sub = oc / 27;
                    int n = oc - sub * 27;
                    smem[(sub * 24 + mcol) * 28 + n] = acc0[rr];
                    int vox1 = 16 + mcol;
                    if (vox1 < 24)
                        smem[(sub * 24 + vox1) * 28 + n] = acc1[rr];
                }
            }
        }
    }
    __syncthreads();

    // stage x neighborhood from xT (overwrites h region): pure b128 copies
    for (int i = t; i < 936; i += 256) {
        int col = i >> 2, chunk = i & 3;     // col = dzdy*26 + px (234 cols)
        int dzdy = col / 26;
        int px = col - dzdy * 26;
        int dz = dzdy / 3, dy = dzdy - dz * 3;
        int zz = min(max(d + dz - 1, 0), 47);
        int yy = min(max(hh + dy - 1, 0), 47);
        int xx = min(max(w0 + px - 1, 0), 47);
        int vox = (zz * 48 + yy) * 48 + xx;
        *(f16x8*)(xh + col * 40 + chunk * 8) =
            *(const f16x8*)(xT + vox * 32 + chunk * 8);
    }
    // softmax over 27 taps, vectorized (192 independent (sub,vox) rows)
    if (t < 192) {
        int sub = t / 24;
        int vox = t - sub * 24;
        float4* p4p = (float4*)(smem + (sub * 24 + vox) * 28);
        float4 v[7];
#pragma unroll
        for (int g = 0; g < 7; ++g) v[g] = p4p[g];
        float mx = fmaxf(fmaxf(v[6].x, v[6].y), v[6].z);
#pragma unroll
        for (int g = 0; g < 6; ++g)
            mx = fmaxf(mx, fmaxf(fmaxf(v[g].x, v[g].y), fmaxf(v[g].z, v[g].w)));
        float s = 0.f;
#pragma unroll
        for (int g = 0; g < 7; ++g) {
            v[g].x = __expf(v[g].x - mx);
            v[g].y = __expf(v[g].y - mx);
            v[g].z = __expf(v[g].z - mx);
            v[g].w = __expf(v[g].w - mx);
        }
        v[6].w = 0.f;
#pragma unroll
        for (int g = 0; g < 7; ++g) s += v[g].x + v[g].y + v[g].z + v[g].w;
        float inv = 1.f / s;
#pragma unroll
        for (int g = 0; g < 7; ++g) {
            v[g].x *= inv; v[g].y *= inv; v[g].z *= inv; v[g].w *= inv;
            p4p[g] = v[g];
        }
    }
    __syncthreads();

    // C: out[c][2d+i][2h+j][2w+k] = sum_n p[sub][vox][n] * x[c][nb(vox,n)]
    float4* smem4 = (float4*)smem;
    int tx = t & 7, ty = t >> 3;
    int cq = ty & 7, sp = ty >> 3;           // sp -> (i,j)
    float4 acc[2][3];
#pragma unroll
    for (int s = 0; s < 2; ++s)
#pragma unroll
        for (int wi = 0; wi < 3; ++wi)
            acc[s][wi] = make_float4(0.f, 0.f, 0.f, 0.f);

#pragma unroll
    for (int g = 0; g < 7; ++g) {
        float4 p4[2][3];
#pragma unroll
        for (int s = 0; s < 2; ++s)
#pragma unroll
            for (int wi = 0; wi < 3; ++wi)
                p4[s][wi] = smem4[((sp * 2 + s) * 24 + tx + wi * 8) * 7 + g];
#pragma unroll
        for (int j = 0; j < 4; ++j) {
            int n = g * 4 + j;
            if (n < 27) {
                int dz = n / 9;
                int rem = n - dz * 9;
                int dy = rem / 3, dx = rem - dy * 3;
#pragma unroll
                for (int wi = 0; wi < 3; ++wi) {
                    int col = (dz * 3 + dy) * 26 + tx + wi * 8 + dx;
                    f16x4 xr = *(const f16x4*)(xh + col * 40 + cq * 4);
                    float4 xv = make_float4((float)xr.x, (float)xr.y,
                                            (float)xr.z, (float)xr.w);
                    fmas4(acc[0][wi], xv, comp4(p4[0][wi], j));
                    fmas4(acc[1][wi], xv, comp4(p4[1][wi], j));
                }
            }
        }
    }

    int i_ = sp >> 1, j_ = sp & 1;
    int rowz = 2 * d + i_;
    int rowy = 2 * hh + j_;
#pragma unroll
    for (int wi = 0; wi < 3; ++wi) {
        int wg = w0 + tx + wi * 8;
#pragma unroll
        for (int cc = 0; cc < 4; ++cc) {
            int c = cq * 4 + cc;
            float2 v;
            v.x = comp4(acc[0][wi], cc);     // k = 0
            v.y = comp4(acc[1][wi], cc);     // k = 1
            *(float2*)(out + (((size_t)c * 96 + rowz) * 96 + rowy) * 96 + 2 * wg) = v;
        }
    }
}

extern "C" void kernel_launch(void* const* d_in, const int* in_sizes, int n_in,
                              void* d_out, int out_size, void* d_ws, size_t ws_size,
                              hipStream_t stream) {
    const float* x    = (const float*)d_in[0];
    const float* feat = (const float*)d_in[1];
    const float* w1   = (const float*)d_in[2];
    const float* b1   = (const float*)d_in[3];
    const float* w2   = (const float*)d_in[4];
    const float* b2   = (const float*)d_in[5];
    float* out = (float*)d_out;

    _Float16* w1h   = (_Float16*)d_ws;                       // 110592 B
    _Float16* w2h   = (_Float16*)((char*)d_ws + 110592);     //  28672 B
    _Float16* featT = (_Float16*)((char*)d_ws + 139264);     // 7,077,888 B
    _Float16* xT    = (_Float16*)((char*)d_ws + 7217152);    // 7,077,888 B
    _Float16* hws   = (_Float16*)((char*)d_ws + 14295040);   // 14,155,776 B

    k_prep<<<272, 256, 0, stream>>>(w1, w2, w1h, w2h);
    k_prepT<<<3456, 256, 0, stream>>>(feat, x, featT, xT);
    k_conv1<<<2304, 256, 0, stream>>>(featT, w1h, b1, hws);
    k_fused<<<4608, 256, 0, stream>>>(xT, hws, w2h, b2, out);
}